// Round 7
// baseline (428.473 us; speedup 1.0000x reference)
//
#include <hip/hip_runtime.h>
#include <cmath>

#define EPSV 1e-5f

typedef short bf16x8 __attribute__((ext_vector_type(8)));
typedef float f32x4 __attribute__((ext_vector_type(4)));
typedef unsigned int u32x2 __attribute__((ext_vector_type(2)));

__device__ __forceinline__ unsigned short f2bf(float f) {
  unsigned u = __float_as_uint(f);
  unsigned r = ((u >> 16) & 1u) + 0x7FFFu;   // RTNE
  return (unsigned short)((u + r) >> 16);
}

__device__ __forceinline__ unsigned cvt_pk_bf16(float lo, float hi) {
  unsigned d;
  asm("v_cvt_pk_bf16_f32 %0, %1, %2" : "=v"(d) : "v"(lo), "v"(hi));
  return d;
}

// ---------------- prep: weights fp32 -> bf16 K-TILE-MAJOR, + softmax(wmask) --------
// Layout: w[kt][n][32 k-elems] (bf16): a wave's fragment load = ONE contiguous 1KB
// segment. w0 re-laid k = ph*196 + q (ph 0..2, q 0..195), K 588->608.
__global__ void prep_conv(const float* __restrict__ w0, const float* __restrict__ w1,
                          const float* __restrict__ w2, unsigned short* __restrict__ w0b,
                          unsigned short* __restrict__ w1b, unsigned short* __restrict__ w2b,
                          const float* __restrict__ wmask, float* __restrict__ wm) {
  if (blockIdx.x >= 2368) {
    int g = (blockIdx.x - 2368) * 4 + (threadIdx.x >> 6);
    int lane = threadIdx.x & 63;
    const float* row = wmask + g * 144;
    float v0 = row[lane], v1 = row[lane + 64];
    float v2 = (lane < 16) ? row[lane + 128] : -1e30f;
    float m = fmaxf(fmaxf(v0, v1), v2);
    for (int off = 32; off; off >>= 1) m = fmaxf(m, __shfl_xor(m, off));
    float e0 = expf(v0 - m), e1 = expf(v1 - m), e2 = (lane < 16) ? expf(v2 - m) : 0.f;
    float s = e0 + e1 + e2;
    for (int off = 32; off; off >>= 1) s += __shfl_xor(s, off);
    float inv = 1.f / s;
    wm[g * 144 + lane] = e0 * inv;
    wm[g * 144 + lane + 64] = e1 * inv;
    if (lane < 16) wm[g * 144 + lane + 128] = e2 * inv;
    return;
  }
  int idx = blockIdx.x * 256 + threadIdx.x;
  if (idx < 512 * 608) {
    int o = idx / 608, k = idx - o * 608;
    float v = 0.f;
    if (k < 588) {
      int ph = (k >= 392) ? 2 : (k >= 196 ? 1 : 0);
      int q = k - ph * 196;
      v = w0[o * 588 + q * 3 + ph];
    }
    w0b[(k >> 5) * 16384 + o * 32 + (k & 31)] = f2bf(v);   // [19][512][32]
    return;
  }
  idx -= 512 * 608;
  if (idx < 384 * 512) {
    int o = idx / 512, k = idx - o * 512;
    w1b[(k >> 5) * 12288 + o * 32 + (k & 31)] = f2bf(w1[idx]);   // [16][384][32]
    return;
  }
  idx -= 384 * 512;
  if (idx < 256 * 384) {
    int o = idx / 384, k = idx - o * 384;
    w2b[(k >> 5) * 8192 + o * 32 + (k & 31)] = f2bf(w2[idx]);    // [12][256][32]
  }
}

// ---------------- fused main ------------------------------------------------------
// R7 = R6 + 2x4 wave grid (M-split): waves own 32 rows x 2x cols -> the shared-A
// LDS read stream (the max pipe) HALVES; B re-reads across the two row-groups are
// L1-absorbed (same addresses, same CU, lockstep).
// LDS map (79.2 KB -> 2 blocks/CU):
//  FT : [0, 77824)      feat 19 tiles x (64 rows x 64B), XOR chunk-swizzle ^((m>>1)&3)
//                       h0 (64 KB) then h1 (48 KB) overlay this region later
//  XB : [77824, 79168)  x cache: 2 batches x 168 f32 (elem 167 zeroed)
#define LDS_XB 77824u

__launch_bounds__(512, 4)
__global__ void fused_main(const float* __restrict__ x, const float* __restrict__ b0,
                           const float* __restrict__ b1, const float* __restrict__ b2,
                           const unsigned short* __restrict__ w0b,
                           const unsigned short* __restrict__ w1b,
                           const unsigned short* __restrict__ w2b,
                           const float* __restrict__ wm, float* __restrict__ out) {
  __shared__ __align__(16) char lds[79168];
  const int tid = threadIdx.x;
  const int wv = tid >> 6, lane = tid & 63;
  const int quad = lane >> 4, l15 = lane & 15;
  const int wr = wv >> 2, wc = wv & 3;          // 2x4 wave grid
  const int mbase = wr * 32;                    // this wave's row base
  const int r0 = blockIdx.x * 64;
  const int bi0 = r0 / 144;
  const int boundary = (bi0 + 1) * 144;

  // ---- x cache: the <=2 batch rows this block touches (1344 B), x[:,167]=0 ----
  if (tid < 336) {
    int bb = (tid >= 168) ? 1 : 0;
    int e = tid - bb * 168;
    int gb = bi0 + bb;
    float v = 0.f;
    if (gb < 1024 && e != 167) v = x[gb * 168 + e];
    ((float*)(lds + LDS_XB))[bb * 168 + e] = v;
  }

  // per-thread feat-gen constants
  const int frow = tid >> 3, fu = tid & 7;
  int fh, fw;
  const float* fxb;
  {
    int fr = r0 + frow;
    int fb = (fr >= boundary) ? 1 : 0;
    int fp = fr - (bi0 + fb) * 144;
    fh = fp / 12;
    fw = fp - fh * 12;
    fxb = (const float*)(lds + LDS_XB) + fb * 168;
  }
  __syncthreads();

  // ---- generate ALL feat tiles (k = ph*196 + q, pad 588->608; 19 x 32-k tiles) ----
  {
    unsigned wbase = frow * 64u + (((fu >> 1) ^ ((frow >> 1) & 3)) * 16u) + (fu & 1) * 8u;
    for (int kt = 0; kt < 19; kt++) {
      int k0 = kt * 32 + fu * 4;
      unsigned lo = 0, hi = 0;
      if (k0 < 588) {
        int ph = (k0 >= 392) ? 2 : (k0 >= 196 ? 1 : 0);
        int q = k0 - ph * 196;
        int i = q / 14, j = q - i * 14;
        float f[4];
#pragma unroll
        for (int e = 0; e < 4; e++) {
          float a = fxb[i * 12 + fh], c = fxb[j * 12 + fw];
          if (ph == 0) f[e] = c - a;
          else {
            float rr = __builtin_amdgcn_rcpf(a + c + EPSV);
            f[e] = (ph == 1) ? (c - a) * rr : c * rr;
          }
          if (++j == 14) { j = 0; i++; }
        }
        lo = cvt_pk_bf16(f[0], f[1]);
        hi = cvt_pk_bf16(f[2], f[3]);
      }
      *(u32x2*)(lds + kt * 4096u + wbase) = u32x2{lo, hi};
    }
  }
  __syncthreads();

  // =================== Layer 0 : feat(608) -> 512 (swapped operands) ===============
  // wave tile: 32 rows x 128 cols. bfr processed in two ct-halves to cap registers.
  {
    f32x4 acc[2][8];
#pragma unroll
    for (int ct = 0; ct < 8; ct++) {
      f32x4 bias = *(const f32x4*)(b0 + wc * 128 + ct * 16 + quad * 4);
      acc[0][ct] = bias;
      acc[1][ct] = bias;
    }

    const char* wb = (const char*)w0b + (unsigned)(wc * 128 + l15) * 64u + quad * 16u;
    const unsigned afb = (unsigned)(mbase + l15) * 64u + ((quad ^ ((l15 >> 1) & 3)) * 16u);

#pragma unroll 1
    for (int kt = 0; kt < 19; kt++) {
      bf16x8 af[2];
#pragma unroll
      for (int rt = 0; rt < 2; rt++)
        af[rt] = *(const bf16x8*)(lds + kt * 4096u + afb + rt * 1024u);
#pragma unroll
      for (int h = 0; h < 2; h++) {
        bf16x8 bfr[4];
#pragma unroll
        for (int c = 0; c < 4; c++)
          bfr[c] = *(const bf16x8*)(wb + (h * 4 + c) * 1024);
        __builtin_amdgcn_s_setprio(1);
#pragma unroll
        for (int rt = 0; rt < 2; rt++)
#pragma unroll
          for (int c = 0; c < 4; c++)
            acc[rt][h * 4 + c] = __builtin_amdgcn_mfma_f32_16x16x32_bf16(bfr[c], af[rt], acc[rt][h * 4 + c], 0, 0, 0);
        __builtin_amdgcn_s_setprio(0);
      }
      wb += 32768;   // next k-tile
    }
    __syncthreads();   // all waves done reading feat; h0 overlays it
    // epilogue: relu -> bf16 h0 at base 0 (chunk-rotate swizzle), packed b64 writes
#pragma unroll
    for (int ct = 0; ct < 8; ct++) {
      int nb = wc * 128 + ct * 16 + quad * 4;
      int kb = nb >> 3;
      unsigned off = (nb & 7) * 2;
#pragma unroll
      for (int rt = 0; rt < 2; rt++) {
        int m = mbase + rt * 16 + l15;
        f32x4 v = acc[rt][ct];
        unsigned lo = cvt_pk_bf16(fmaxf(v[0], 0.f), fmaxf(v[1], 0.f));
        unsigned hi = cvt_pk_bf16(fmaxf(v[2], 0.f), fmaxf(v[3], 0.f));
        *(u32x2*)(lds + m * 1024u + ((kb + m) & 63) * 16u + off) = u32x2{lo, hi};
      }
    }
  }
  __syncthreads();   // h0 visible

  // =================== Layer 1 : 512 -> 384 (swapped operands) =====================
  // wave tile: 32 rows x 96 cols.
  {
    f32x4 acc[2][6];
#pragma unroll
    for (int ct = 0; ct < 6; ct++) {
      f32x4 bias = *(const f32x4*)(b1 + wc * 96 + ct * 16 + quad * 4);
      acc[0][ct] = bias;
      acc[1][ct] = bias;
    }

    const char* wb = (const char*)w1b + (unsigned)(wc * 96 + l15) * 64u + quad * 16u;

#pragma unroll 1
    for (int kt = 0; kt < 16; kt++) {
      bf16x8 bfr[6], af[2];
#pragma unroll
      for (int ct = 0; ct < 6; ct++)
        bfr[ct] = *(const bf16x8*)(wb + ct * 1024);
#pragma unroll
      for (int rt = 0; rt < 2; rt++) {
        int m = mbase + rt * 16 + l15;
        af[rt] = *(const bf16x8*)(lds + m * 1024u + (((kt * 4 + quad) + m) & 63) * 16u);
      }
      __builtin_amdgcn_s_setprio(1);
#pragma unroll
      for (int rt = 0; rt < 2; rt++)
#pragma unroll
        for (int ct = 0; ct < 6; ct++)
          acc[rt][ct] = __builtin_amdgcn_mfma_f32_16x16x32_bf16(bfr[ct], af[rt], acc[rt][ct], 0, 0, 0);
      __builtin_amdgcn_s_setprio(0);
      wb += 24576;
    }
    __syncthreads();   // all waves done READING h0 before h1 overwrites the region
    // epilogue -> h1 at base 0 (48 chunks/row, rotate mod 48), packed b64 writes
#pragma unroll
    for (int ct = 0; ct < 6; ct++) {
      int nb = wc * 96 + ct * 16 + quad * 4;
      int kb = nb >> 3;
      unsigned off = (nb & 7) * 2;
#pragma unroll
      for (int rt = 0; rt < 2; rt++) {
        int m = mbase + rt * 16 + l15;
        int s = kb + m;
        if (s >= 48) s -= 48;
        if (s >= 48) s -= 48;
        f32x4 v = acc[rt][ct];
        unsigned lo = cvt_pk_bf16(fmaxf(v[0], 0.f), fmaxf(v[1], 0.f));
        unsigned hi = cvt_pk_bf16(fmaxf(v[2], 0.f), fmaxf(v[3], 0.f));
        *(u32x2*)(lds + m * 768u + s * 16u + off) = u32x2{lo, hi};
      }
    }
  }
  __syncthreads();   // h1 visible

  // =================== Layer 2 : 384 -> 256, fused reduction =======================
  // wave tile: 32 rows x 64 cols. Original operand order: lane owns col.
  {
    f32x4 acc[2][4];
#pragma unroll
    for (int ct = 0; ct < 4; ct++) {
      float bias = b2[wc * 64 + ct * 16 + l15];
      acc[0][ct] = f32x4{bias, bias, bias, bias};
      acc[1][ct] = f32x4{0.f, 0.f, 0.f, 0.f};   // bias only once per col (wr=0 adds it)
    }
    // NOTE: bias must be added exactly once per (row-block? no) -- bias applies per
    // OUTPUT element (row,col); both rt accs are distinct rows, so bias belongs in
    // BOTH. Revert: add to both.
#pragma unroll
    for (int ct = 0; ct < 4; ct++) acc[1][ct] = acc[0][ct];

    const char* wb = (const char*)w2b + (unsigned)(wc * 64 + l15) * 64u + quad * 16u;

#pragma unroll 1
    for (int kt = 0; kt < 12; kt++) {
      bf16x8 bfr[4], af[2];
#pragma unroll
      for (int ct = 0; ct < 4; ct++)
        bfr[ct] = *(const bf16x8*)(wb + ct * 1024);
#pragma unroll
      for (int rt = 0; rt < 2; rt++) {
        int m = mbase + rt * 16 + l15;
        int s = (kt * 4 + quad) + m;
        if (s >= 48) s -= 48;
        if (s >= 48) s -= 48;
        af[rt] = *(const bf16x8*)(lds + m * 768u + s * 16u);
      }
      __builtin_amdgcn_s_setprio(1);
#pragma unroll
      for (int rt = 0; rt < 2; rt++)
#pragma unroll
        for (int ct = 0; ct < 4; ct++)
          acc[rt][ct] = __builtin_amdgcn_mfma_f32_16x16x32_bf16(af[rt], bfr[ct], acc[rt][ct], 0, 0, 0);
      __builtin_amdgcn_s_setprio(0);
      wb += 16384;
    }

    // epilogue: relu(h2) * softmax-wm, reduce this wave's 32 rows, atomicAdd to out
#pragma unroll
    for (int ct = 0; ct < 4; ct++) {
      int col = wc * 64 + ct * 16 + l15;
      const float* wmg = wm + (col >> 4) * 144;
      float s0 = 0.f, s1 = 0.f;
#pragma unroll
      for (int rt = 0; rt < 2; rt++)
#pragma unroll
        for (int vi = 0; vi < 4; vi++) {
          int r = r0 + mbase + rt * 16 + quad * 4 + vi;
          float v = fmaxf(acc[rt][ct][vi], 0.f);
          if (r < boundary) s0 += v * wmg[r - bi0 * 144];
          else              s1 += v * wmg[r - boundary];
        }
      s0 += __shfl_xor(s0, 16); s0 += __shfl_xor(s0, 32);
      s1 += __shfl_xor(s1, 16); s1 += __shfl_xor(s1, 32);
      if (quad == 0) {
        atomicAdd(out + bi0 * 256 + col, s0);
        if (boundary < r0 + 64) atomicAdd(out + (bi0 + 1) * 256 + col, s1);
      }
    }
  }
}

extern "C" void kernel_launch(void* const* d_in, const int* in_sizes, int n_in,
                              void* d_out, int out_size, void* d_ws, size_t ws_size,
                              hipStream_t stream) {
  (void)in_sizes; (void)n_in; (void)ws_size;
  const float* x     = (const float*)d_in[0];
  const float* w0    = (const float*)d_in[1];
  const float* b0    = (const float*)d_in[2];
  const float* w1    = (const float*)d_in[3];
  const float* b1    = (const float*)d_in[4];
  const float* w2    = (const float*)d_in[5];
  const float* b2    = (const float*)d_in[6];
  const float* wmask = (const float*)d_in[7];
  float* out = (float*)d_out;
  char* ws = (char*)d_ws;
  float* wm = (float*)ws;                                        // 16*144*4 = 9216
  unsigned short* w0b = (unsigned short*)(ws + 9216);            // 512*608*2 = 622592
  unsigned short* w1b = (unsigned short*)(ws + 9216 + 622592);   // 384*512*2 = 393216
  unsigned short* w2b = (unsigned short*)(ws + 9216 + 622592 + 393216);  // 256*384*2

  hipMemsetAsync(d_out, 0, (size_t)out_size * sizeof(float), stream);
  prep_conv<<<2372, 256, 0, stream>>>(w0, w1, w2, w0b, w1b, w2b, wmask, wm);
  fused_main<<<2304, 512, 0, stream>>>(x, b0, b1, b2, w0b, w1b, w2b, wm, out);
}

// Round 8
// 278.402 us; speedup vs baseline: 1.5390x; 1.5390x over previous
//
#include <hip/hip_runtime.h>
#include <cmath>

#define EPSV 1e-5f

typedef short bf16x8 __attribute__((ext_vector_type(8)));
typedef float f32x4 __attribute__((ext_vector_type(4)));
typedef unsigned int u32x2 __attribute__((ext_vector_type(2)));

__device__ __forceinline__ unsigned short f2bf(float f) {
  unsigned u = __float_as_uint(f);
  unsigned r = ((u >> 16) & 1u) + 0x7FFFu;   // RTNE
  return (unsigned short)((u + r) >> 16);
}

__device__ __forceinline__ unsigned cvt_pk_bf16(float lo, float hi) {
  unsigned d;
  asm("v_cvt_pk_bf16_f32 %0, %1, %2" : "=v"(d) : "v"(lo), "v"(hi));
  return d;
}

// ---------------- prep: weights fp32 -> bf16 K-TILE-MAJOR, + softmax(wmask) --------
// Layout: w[kt][n][32 k-elems] (bf16): a wave's fragment load = ONE contiguous 1KB
// segment. w0 re-laid k = ph*196 + q (ph 0..2, q 0..195), K 588->608.
__global__ void prep_conv(const float* __restrict__ w0, const float* __restrict__ w1,
                          const float* __restrict__ w2, unsigned short* __restrict__ w0b,
                          unsigned short* __restrict__ w1b, unsigned short* __restrict__ w2b,
                          const float* __restrict__ wmask, float* __restrict__ wm) {
  if (blockIdx.x >= 2368) {
    int g = (blockIdx.x - 2368) * 4 + (threadIdx.x >> 6);
    int lane = threadIdx.x & 63;
    const float* row = wmask + g * 144;
    float v0 = row[lane], v1 = row[lane + 64];
    float v2 = (lane < 16) ? row[lane + 128] : -1e30f;
    float m = fmaxf(fmaxf(v0, v1), v2);
    for (int off = 32; off; off >>= 1) m = fmaxf(m, __shfl_xor(m, off));
    float e0 = expf(v0 - m), e1 = expf(v1 - m), e2 = (lane < 16) ? expf(v2 - m) : 0.f;
    float s = e0 + e1 + e2;
    for (int off = 32; off; off >>= 1) s += __shfl_xor(s, off);
    float inv = 1.f / s;
    wm[g * 144 + lane] = e0 * inv;
    wm[g * 144 + lane + 64] = e1 * inv;
    if (lane < 16) wm[g * 144 + lane + 128] = e2 * inv;
    return;
  }
  int idx = blockIdx.x * 256 + threadIdx.x;
  if (idx < 512 * 608) {
    int o = idx / 608, k = idx - o * 608;
    float v = 0.f;
    if (k < 588) {
      int ph = (k >= 392) ? 2 : (k >= 196 ? 1 : 0);
      int q = k - ph * 196;
      v = w0[o * 588 + q * 3 + ph];
    }
    w0b[(k >> 5) * 16384 + o * 32 + (k & 31)] = f2bf(v);   // [19][512][32]
    return;
  }
  idx -= 512 * 608;
  if (idx < 384 * 512) {
    int o = idx / 512, k = idx - o * 512;
    w1b[(k >> 5) * 12288 + o * 32 + (k & 31)] = f2bf(w1[idx]);   // [16][384][32]
    return;
  }
  idx -= 384 * 512;
  if (idx < 256 * 384) {
    int o = idx / 384, k = idx - o * 384;
    w2b[(k >> 5) * 8192 + o * 32 + (k & 31)] = f2bf(w2[idx]);    // [12][256][32]
  }
}

// ---------------- fused main ------------------------------------------------------
// R8 = R6 (best: 248us) + STAGGERED K-ORDER: each wave starts its K-loop at tile
// (blockIdx.x + wv) mod NT and wraps. All CUs otherwise read the SAME 1.2 MB weight
// array in lockstep -> correlated L2 slice hotspot (R7 evidence: B-VMEM is the
// saturated pipe). Staggering decorrelates the stream across L2 slices. fp32
// accumulation order over K is irrelevant; feat is fully pre-generated.
// LDS map (79.2 KB -> 2 blocks/CU):
//  FT : [0, 77824)      feat 19 tiles x (64 rows x 64B), XOR chunk-swizzle ^((m>>1)&3)
//                       h0 (64 KB) then h1 (48 KB) overlay this region later
//  XB : [77824, 79168)  x cache: 2 batches x 168 f32 (elem 167 zeroed)
#define LDS_XB 77824u

__launch_bounds__(512, 4)
__global__ void fused_main(const float* __restrict__ x, const float* __restrict__ b0,
                           const float* __restrict__ b1, const float* __restrict__ b2,
                           const unsigned short* __restrict__ w0b,
                           const unsigned short* __restrict__ w1b,
                           const unsigned short* __restrict__ w2b,
                           const float* __restrict__ wm, float* __restrict__ out) {
  __shared__ __align__(16) char lds[79168];
  const int tid = threadIdx.x;
  const int wv = tid >> 6, lane = tid & 63;
  const int quad = lane >> 4, l15 = lane & 15;
  const int r0 = blockIdx.x * 64;
  const int bi0 = r0 / 144;
  const int boundary = (bi0 + 1) * 144;

  // ---- x cache: the <=2 batch rows this block touches (1344 B), x[:,167]=0 ----
  if (tid < 336) {
    int bb = (tid >= 168) ? 1 : 0;
    int e = tid - bb * 168;
    int gb = bi0 + bb;
    float v = 0.f;
    if (gb < 1024 && e != 167) v = x[gb * 168 + e];
    ((float*)(lds + LDS_XB))[bb * 168 + e] = v;
  }

  // per-thread feat-gen constants
  const int frow = tid >> 3, fu = tid & 7;
  int fh, fw;
  const float* fxb;
  {
    int fr = r0 + frow;
    int fb = (fr >= boundary) ? 1 : 0;
    int fp = fr - (bi0 + fb) * 144;
    fh = fp / 12;
    fw = fp - fh * 12;
    fxb = (const float*)(lds + LDS_XB) + fb * 168;
  }
  __syncthreads();

  // ---- generate ALL feat tiles (k = ph*196 + q, pad 588->608; 19 x 32-k tiles) ----
  {
    unsigned wbase = frow * 64u + (((fu >> 1) ^ ((frow >> 1) & 3)) * 16u) + (fu & 1) * 8u;
    for (int kt = 0; kt < 19; kt++) {
      int k0 = kt * 32 + fu * 4;
      unsigned lo = 0, hi = 0;
      if (k0 < 588) {
        int ph = (k0 >= 392) ? 2 : (k0 >= 196 ? 1 : 0);
        int q = k0 - ph * 196;
        int i = q / 14, j = q - i * 14;
        float f[4];
#pragma unroll
        for (int e = 0; e < 4; e++) {
          float a = fxb[i * 12 + fh], c = fxb[j * 12 + fw];
          if (ph == 0) f[e] = c - a;
          else {
            float rr = __builtin_amdgcn_rcpf(a + c + EPSV);
            f[e] = (ph == 1) ? (c - a) * rr : c * rr;
          }
          if (++j == 14) { j = 0; i++; }
        }
        lo = cvt_pk_bf16(f[0], f[1]);
        hi = cvt_pk_bf16(f[2], f[3]);
      }
      *(u32x2*)(lds + kt * 4096u + wbase) = u32x2{lo, hi};
    }
  }
  __syncthreads();

  // =================== Layer 0 : feat(608) -> 512 (swapped operands) ===============
  {
    f32x4 acc[4][4];
#pragma unroll
    for (int ct = 0; ct < 4; ct++) {
      f32x4 bias = *(const f32x4*)(b0 + wv * 64 + ct * 16 + quad * 4);
#pragma unroll
      for (int rt = 0; rt < 4; rt++) acc[rt][ct] = bias;
    }

    // k-tile-major: wave's load for ct = ONE contiguous 1KB segment.
    const char* wb = (const char*)w0b + (unsigned)(wv * 64 + l15) * 64u + quad * 16u;
    const unsigned afb = l15 * 64u + ((quad ^ ((l15 >> 1) & 3)) * 16u);
    unsigned ko = ((blockIdx.x + wv) % 19u) * 32768u;   // staggered start tile

#pragma unroll 1
    for (int it = 0; it < 19; it++) {
      bf16x8 bfr[4], af[4];
#pragma unroll
      for (int ct = 0; ct < 4; ct++)
        bfr[ct] = *(const bf16x8*)(wb + ko + ct * 1024);
#pragma unroll
      for (int rt = 0; rt < 4; rt++)
        af[rt] = *(const bf16x8*)(lds + (ko >> 3) + afb + rt * 1024u);   // ko/8 = kt*4096
      __builtin_amdgcn_s_setprio(1);
#pragma unroll
      for (int rt = 0; rt < 4; rt++)
#pragma unroll
        for (int ct = 0; ct < 4; ct++)
          acc[rt][ct] = __builtin_amdgcn_mfma_f32_16x16x32_bf16(bfr[ct], af[rt], acc[rt][ct], 0, 0, 0);
      __builtin_amdgcn_s_setprio(0);
      ko += 32768u;
      if (ko == 19u * 32768u) ko = 0u;
    }
    __syncthreads();   // all waves done reading feat; h0 overlays it
    // epilogue: relu -> bf16 h0 at base 0 (chunk-rotate swizzle), packed b64 writes
#pragma unroll
    for (int ct = 0; ct < 4; ct++) {
      int nb = wv * 64 + ct * 16 + quad * 4;
      int kb = nb >> 3;
      unsigned off = (nb & 7) * 2;
#pragma unroll
      for (int rt = 0; rt < 4; rt++) {
        int m = rt * 16 + l15;
        f32x4 v = acc[rt][ct];
        unsigned lo = cvt_pk_bf16(fmaxf(v[0], 0.f), fmaxf(v[1], 0.f));
        unsigned hi = cvt_pk_bf16(fmaxf(v[2], 0.f), fmaxf(v[3], 0.f));
        *(u32x2*)(lds + m * 1024u + ((kb + m) & 63) * 16u + off) = u32x2{lo, hi};
      }
    }
  }
  __syncthreads();   // h0 visible

  // =================== Layer 1 : 512 -> 384 (swapped operands, barrier-free) =======
  {
    f32x4 acc[4][3];
#pragma unroll
    for (int ct = 0; ct < 3; ct++) {
      f32x4 bias = *(const f32x4*)(b1 + wv * 48 + ct * 16 + quad * 4);
#pragma unroll
      for (int rt = 0; rt < 4; rt++) acc[rt][ct] = bias;
    }

    const char* wb = (const char*)w1b + (unsigned)(wv * 48 + l15) * 64u + quad * 16u;
    unsigned kk = (blockIdx.x + wv) & 15u;              // staggered start tile
    unsigned ko = kk * 24576u;

#pragma unroll 1
    for (int it = 0; it < 16; it++) {
      bf16x8 bfr[3], af[4];
#pragma unroll
      for (int ct = 0; ct < 3; ct++)
        bfr[ct] = *(const bf16x8*)(wb + ko + ct * 1024);
#pragma unroll
      for (int rt = 0; rt < 4; rt++) {
        int m = rt * 16 + l15;
        af[rt] = *(const bf16x8*)(lds + m * 1024u + (((kk * 4 + quad) + m) & 63) * 16u);
      }
      __builtin_amdgcn_s_setprio(1);
#pragma unroll
      for (int rt = 0; rt < 4; rt++)
#pragma unroll
        for (int ct = 0; ct < 3; ct++)
          acc[rt][ct] = __builtin_amdgcn_mfma_f32_16x16x32_bf16(bfr[ct], af[rt], acc[rt][ct], 0, 0, 0);
      __builtin_amdgcn_s_setprio(0);
      ko += 24576u;
      kk++;
      if (kk == 16u) { kk = 0u; ko = 0u; }
    }
    __syncthreads();   // all waves done READING h0 before h1 overwrites the region
    // epilogue -> h1 at base 0 (48 chunks/row, rotate mod 48), packed b64 writes
#pragma unroll
    for (int ct = 0; ct < 3; ct++) {
      int nb = wv * 48 + ct * 16 + quad * 4;
      int kb = nb >> 3;
      unsigned off = (nb & 7) * 2;
#pragma unroll
      for (int rt = 0; rt < 4; rt++) {
        int m = rt * 16 + l15;
        int s = kb + m;
        if (s >= 48) s -= 48;
        if (s >= 48) s -= 48;
        f32x4 v = acc[rt][ct];
        unsigned lo = cvt_pk_bf16(fmaxf(v[0], 0.f), fmaxf(v[1], 0.f));
        unsigned hi = cvt_pk_bf16(fmaxf(v[2], 0.f), fmaxf(v[3], 0.f));
        *(u32x2*)(lds + m * 768u + s * 16u + off) = u32x2{lo, hi};
      }
    }
  }
  __syncthreads();   // h1 visible

  // =================== Layer 2 : 384 -> 256, fused reduction (barrier-free) ========
  // Original operand order: lane owns col => row-reduction via 2 shfls.
  {
    f32x4 acc[4][2];
#pragma unroll
    for (int ct = 0; ct < 2; ct++) {
      float bias = b2[wv * 32 + ct * 16 + l15];
#pragma unroll
      for (int rt = 0; rt < 4; rt++) acc[rt][ct] = f32x4{bias, bias, bias, bias};
    }

    const char* wb = (const char*)w2b + (unsigned)(wv * 32 + l15) * 64u + quad * 16u;
    unsigned kk = (blockIdx.x + wv) % 12u;              // staggered start tile
    unsigned ko = kk * 16384u;

#pragma unroll 1
    for (int it = 0; it < 12; it++) {
      bf16x8 bfr[2], af[4];
#pragma unroll
      for (int ct = 0; ct < 2; ct++)
        bfr[ct] = *(const bf16x8*)(wb + ko + ct * 1024);
#pragma unroll
      for (int rt = 0; rt < 4; rt++) {
        int m = rt * 16 + l15;
        int s = (kk * 4 + quad) + m;
        if (s >= 48) s -= 48;
        if (s >= 48) s -= 48;
        af[rt] = *(const bf16x8*)(lds + m * 768u + s * 16u);
      }
      __builtin_amdgcn_s_setprio(1);
#pragma unroll
      for (int rt = 0; rt < 4; rt++)
#pragma unroll
        for (int ct = 0; ct < 2; ct++)
          acc[rt][ct] = __builtin_amdgcn_mfma_f32_16x16x32_bf16(af[rt], bfr[ct], acc[rt][ct], 0, 0, 0);
      __builtin_amdgcn_s_setprio(0);
      ko += 16384u;
      kk++;
      if (kk == 12u) { kk = 0u; ko = 0u; }
    }

    // epilogue: relu(h2) * softmax-wm, reduce over rows, atomicAdd into out
#pragma unroll
    for (int ct = 0; ct < 2; ct++) {
      int col = wv * 32 + ct * 16 + l15;
      const float* wmg = wm + (col >> 4) * 144;
      float s0 = 0.f, s1 = 0.f;
#pragma unroll
      for (int rt = 0; rt < 4; rt++)
#pragma unroll
        for (int vi = 0; vi < 4; vi++) {
          int r = r0 + rt * 16 + quad * 4 + vi;
          float v = fmaxf(acc[rt][ct][vi], 0.f);
          if (r < boundary) s0 += v * wmg[r - bi0 * 144];
          else              s1 += v * wmg[r - boundary];
        }
      s0 += __shfl_xor(s0, 16); s0 += __shfl_xor(s0, 32);
      s1 += __shfl_xor(s1, 16); s1 += __shfl_xor(s1, 32);
      if (quad == 0) {
        atomicAdd(out + bi0 * 256 + col, s0);
        if (boundary < r0 + 64) atomicAdd(out + (bi0 + 1) * 256 + col, s1);
      }
    }
  }
}

extern "C" void kernel_launch(void* const* d_in, const int* in_sizes, int n_in,
                              void* d_out, int out_size, void* d_ws, size_t ws_size,
                              hipStream_t stream) {
  (void)in_sizes; (void)n_in; (void)ws_size;
  const float* x     = (const float*)d_in[0];
  const float* w0    = (const float*)d_in[1];
  const float* b0    = (const float*)d_in[2];
  const float* w1    = (const float*)d_in[3];
  const float* b1    = (const float*)d_in[4];
  const float* w2    = (const float*)d_in[5];
  const float* b2    = (const float*)d_in[6];
  const float* wmask = (const float*)d_in[7];
  float* out = (float*)d_out;
  char* ws = (char*)d_ws;
  float* wm = (float*)ws;                                        // 16*144*4 = 9216
  unsigned short* w0b = (unsigned short*)(ws + 9216);            // 512*608*2 = 622592
  unsigned short* w1b = (unsigned short*)(ws + 9216 + 622592);   // 384*512*2 = 393216
  unsigned short* w2b = (unsigned short*)(ws + 9216 + 622592 + 393216);  // 256*384*2

  hipMemsetAsync(d_out, 0, (size_t)out_size * sizeof(float), stream);
  prep_conv<<<2372, 256, 0, stream>>>(w0, w1, w2, w0b, w1b, w2b, wmask, wm);
  fused_main<<<2304, 512, 0, stream>>>(x, b0, b1, b2, w0b, w1b, w2b, wm, out);
}